// Round 1
// baseline (182.416 us; speedup 1.0000x reference)
//
#include <hip/hip_runtime.h>

// DynamicRouting (CapsNet) on MI355X.
// B=16, I=32, C=8, J=10, D=16, H=W=6 -> DHW=576. num_routing=3 (fixed).
//
// Key factorization: c[i,j] broadcasts over C and v doesn't depend on (i,c),
// so precompute U[b,i,j,dhw] = sum_c u_hat[b,i,c,j,dhw] (11.8 MB) and run all
// routing math on U. u_hat (94.4 MB) is read from HBM exactly once.

#define NB   16
#define NI   32
#define NC   8
#define NJ   10
#define ND   16
#define NHW  36
#define NDHW 576
#define EPSV 1e-7f

static __device__ __forceinline__ double wave_reduce(double a) {
    #pragma unroll
    for (int off = 32; off > 0; off >>= 1) a += __shfl_down(a, off);
    return a;
}

// ---------------------------------------------------------------------------
// Kernel 1: U[b,i,j,dhw] = sum_c u_hat[b,i,c,j,dhw]   (float4-vectorized)
// u_hat float4 index: (bi*NC + c)*(NJ*144) + j*144 + f4,  f4 in [0,144)
// ---------------------------------------------------------------------------
__global__ __launch_bounds__(256) void reduce_c_kernel(
    const float4* __restrict__ uh, float4* __restrict__ U)
{
    int t = blockIdx.x * 256 + threadIdx.x;     // < 16*32*10*144 = 737280
    int f4 = t % 144;
    int j  = (t / 144) % NJ;
    int bi = t / (144 * NJ);                    // b*NI + i
    const float4* p = uh + ((size_t)bi * NC) * (NJ * 144) + j * 144 + f4;
    float4 acc = make_float4(0.f, 0.f, 0.f, 0.f);
    #pragma unroll
    for (int c = 0; c < NC; ++c) {
        float4 v = p[(size_t)c * (NJ * 144)];
        acc.x += v.x; acc.y += v.y; acc.z += v.z; acc.w += v.w;
    }
    U[t] = acc;
}

// ---------------------------------------------------------------------------
// Kernel 2: per block (b,j): softmax(b_ij) fused; s = sum_i c[i,j]*U + bias;
//           n1[b] += sum_dhw |s|  (double atomics)
// ---------------------------------------------------------------------------
__global__ __launch_bounds__(NDHW) void s_n1_kernel(
    const float* __restrict__ U, const float* __restrict__ bias,
    const float* __restrict__ b_ij, float* __restrict__ s,
    double* __restrict__ n1)
{
    int blk = blockIdx.x;                 // b*NJ + j
    int b = blk / NJ, j = blk - b * NJ;
    int tid = threadIdx.x;                // dhw in [0,576)

    __shared__ float c_sh[NI];
    if (tid < NI) {
        float row[NJ];
        float m = -1e30f;
        #pragma unroll
        for (int jj = 0; jj < NJ; ++jj) {
            row[jj] = b_ij[tid * NJ + jj];
            m = fmaxf(m, row[jj]);
        }
        float sum = 0.f;
        #pragma unroll
        for (int jj = 0; jj < NJ; ++jj) sum += expf(row[jj] - m);
        c_sh[tid] = expf(row[j] - m) / sum;
    }
    __syncthreads();

    float sv = bias[j * ND + tid / NHW];
    const float* Ub = U + ((size_t)(b * NI) * NJ + j) * NDHW + tid;
    #pragma unroll 8
    for (int i = 0; i < NI; ++i)
        sv += c_sh[i] * Ub[(size_t)i * NJ * NDHW];
    s[((size_t)b * NJ + j) * NDHW + tid] = sv;

    // block-reduce |sv| in double (9 waves)
    double a = wave_reduce((double)fabsf(sv));
    __shared__ double wpart[NDHW / 64];
    if ((tid & 63) == 0) wpart[tid >> 6] = a;
    __syncthreads();
    if (tid == 0) {
        double t = wpart[0];
        #pragma unroll
        for (int k = 1; k < NDHW / 64; ++k) t += wpart[k];
        atomicAdd(&n1[b], t);
    }
}

// ---------------------------------------------------------------------------
// Kernel 3: per block (i,j): b_ij[i,j] += sum_{b,dhw} U * (scale[b]*s)
// ---------------------------------------------------------------------------
__global__ __launch_bounds__(256) void agree_kernel(
    const float* __restrict__ U, const float* __restrict__ s,
    const double* __restrict__ n1, float* __restrict__ b_ij)
{
    int ij = blockIdx.x;
    int i = ij / NJ, j = ij - i * NJ;
    int tid = threadIdx.x;

    __shared__ double sc_sh[NB];
    if (tid < NB) {
        double n1v = n1[tid];
        double nsq = n1v * n1v;
        sc_sh[tid] = (nsq / (1.0 + nsq)) / (n1v + (double)EPSV);
    }
    __syncthreads();

    double acc = 0.0;
    for (int t = tid; t < NB * NDHW; t += 256) {
        int b = t / NDHW, dhw = t - b * NDHW;
        float Uv = U[((size_t)(b * NI + i) * NJ + j) * NDHW + dhw];
        float sv = s[((size_t)b * NJ + j) * NDHW + dhw];
        acc += (double)Uv * (double)sv * sc_sh[b];
    }
    acc = wave_reduce(acc);
    __shared__ double wpart[4];
    if ((tid & 63) == 0) wpart[tid >> 6] = acc;
    __syncthreads();
    if (tid == 0)
        b_ij[i * NJ + j] += (float)(wpart[0] + wpart[1] + wpart[2] + wpart[3]);
}

// ---------------------------------------------------------------------------
// Kernel 4: v = (n1^2/(1+n1^2)) * (s/(n1+eps))   -> d_out  [B,J,D,H,W]
// ---------------------------------------------------------------------------
__global__ __launch_bounds__(256) void vout_kernel(
    const float* __restrict__ s, const double* __restrict__ n1,
    float* __restrict__ out)
{
    int idx = blockIdx.x * 256 + threadIdx.x;   // < 92160
    int b = idx / (NJ * NDHW);
    float n1f = (float)n1[b];
    float nsq = n1f * n1f;
    out[idx] = (nsq / (1.f + nsq)) * (s[idx] / (n1f + EPSV));
}

extern "C" void kernel_launch(void* const* d_in, const int* in_sizes, int n_in,
                              void* d_out, int out_size, void* d_ws, size_t ws_size,
                              hipStream_t stream)
{
    const float* u_hat = (const float*)d_in[0];
    const float* bias  = (const float*)d_in[1];
    // d_in[2] = num_routing, fixed at 3 by the problem.

    float*  U   = (float*)d_ws;                         // 2,949,120 floats
    float*  s   = U + (size_t)NB * NI * NJ * NDHW;      //    92,160 floats
    float*  bij = s + (size_t)NB * NJ * NDHW;           //       320 floats
    double* n1  = (double*)(bij + NI * NJ);             // 3*16 doubles (8B aligned)
    float*  out = (float*)d_out;

    // zero b_ij + all 3 n1 slices (ws is poisoned 0xAA before every launch)
    hipMemsetAsync(bij, 0, NI * NJ * sizeof(float) + 3 * NB * sizeof(double), stream);

    reduce_c_kernel<<<(NB * NI * NJ * 144) / 256, 256, 0, stream>>>(
        (const float4*)u_hat, (float4*)U);

    for (int r = 0; r < 3; ++r) {
        s_n1_kernel<<<NB * NJ, NDHW, 0, stream>>>(U, bias, bij, s, n1 + r * NB);
        if (r < 2)
            agree_kernel<<<NI * NJ, 256, 0, stream>>>(U, s, n1 + r * NB, bij);
        else
            vout_kernel<<<(NB * NJ * NDHW) / 256, 256, 0, stream>>>(s, n1 + r * NB, out);
    }
}